// Round 1
// baseline (3315.761 us; speedup 1.0000x reference)
//
#include <hip/hip_runtime.h>

// Problem constants (fixed by harness)
#define BB 256
#define TT 64
#define II 512
#define HH 512
#define CC 97
#define SS 26      // MAXLEN+1
#define GG 2048    // 4H
#define KX 1024    // packed K for gates GEMM (ctx 512 | h 512)

// ---------------------------------------------------------------------------
// K_init: zero xA, xB, cbuf (they sit contiguously at start of ws)
// ---------------------------------------------------------------------------
__global__ __launch_bounds__(256) void k_init(float4* __restrict__ p, int n4) {
  int i = blockIdx.x * 256 + threadIdx.x;
  if (i < n4) p[i] = make_float4(0.f, 0.f, 0.f, 0.f);
}

// ---------------------------------------------------------------------------
// K_prep: pack W_ih[:, :512] | W_hh into Wp [2048][1024] with gate-interleaved
// rows r = j*4+q  (orig gate row g = q*512+j), bias bp[r] = b_ih[g]+b_hh[g],
// one-hot columns Woh[r][c] = W_ih[g][512+c]
// ---------------------------------------------------------------------------
__global__ __launch_bounds__(256) void k_prep(const float* __restrict__ W_ih, const float* __restrict__ b_ih,
                                              const float* __restrict__ W_hh, const float* __restrict__ b_hh,
                                              float* __restrict__ Wp, float* __restrict__ bp,
                                              float* __restrict__ Woh) {
  int r = blockIdx.x;            // 0..2047 packed row
  int q = r & 3, j = r >> 2;
  int g = q * 512 + j;           // original gate row
  int tid = threadIdx.x;
  for (int k = tid; k < 512; k += 256) {
    Wp[(size_t)r * KX + k]       = W_ih[(size_t)g * 609 + k];
    Wp[(size_t)r * KX + 512 + k] = W_hh[(size_t)g * 512 + k];
  }
  if (tid < CC) Woh[(size_t)r * CC + tid] = W_ih[(size_t)g * 609 + 512 + tid];
  if (tid == 0) bp[r] = b_ih[g] + b_hh[g];
}

// ---------------------------------------------------------------------------
// K0: proj = batch_hidden @ W_i2h^T   (M=16384, N=512, K=512)
// f32 tiles 128x128x16, micro 8x8, 256 threads, grid 512
// ---------------------------------------------------------------------------
__global__ __launch_bounds__(256) void k0_proj(const float* __restrict__ A, const float* __restrict__ Bw,
                                               float* __restrict__ Cp) {
  const int M_ = 16384, N_ = 512, K_ = 512;
  __shared__ float As[16][128];
  __shared__ float Bs[16][128];
  int m0 = (blockIdx.x >> 2) * 128;
  int n0 = (blockIdx.x & 3) * 128;
  int tid = threadIdx.x;
  int tm = (tid >> 4) * 8, tn = (tid & 15) * 8;
  float acc[8][8] = {};
  for (int k0 = 0; k0 < K_; k0 += 16) {
#pragma unroll
    for (int i = 0; i < 2; ++i) {
      int f = tid + i * 256;           // 0..511
      int row = f >> 2, c4 = (f & 3) * 4;
      float4 va = *(const float4*)&A[(size_t)(m0 + row) * K_ + k0 + c4];
      As[c4 + 0][row] = va.x; As[c4 + 1][row] = va.y; As[c4 + 2][row] = va.z; As[c4 + 3][row] = va.w;
      float4 vb = *(const float4*)&Bw[(size_t)(n0 + row) * K_ + k0 + c4];
      Bs[c4 + 0][row] = vb.x; Bs[c4 + 1][row] = vb.y; Bs[c4 + 2][row] = vb.z; Bs[c4 + 3][row] = vb.w;
    }
    __syncthreads();
#pragma unroll
    for (int k = 0; k < 16; ++k) {
      float4 a0 = *(const float4*)&As[k][tm];
      float4 a1 = *(const float4*)&As[k][tm + 4];
      float4 b0 = *(const float4*)&Bs[k][tn];
      float4 b1 = *(const float4*)&Bs[k][tn + 4];
      float av[8] = {a0.x, a0.y, a0.z, a0.w, a1.x, a1.y, a1.z, a1.w};
      float bv[8] = {b0.x, b0.y, b0.z, b0.w, b1.x, b1.y, b1.z, b1.w};
#pragma unroll
      for (int r = 0; r < 8; ++r)
#pragma unroll
        for (int c = 0; c < 8; ++c) acc[r][c] += av[r] * bv[c];
    }
    __syncthreads();
  }
#pragma unroll
  for (int r = 0; r < 8; ++r) {
    float4* o = (float4*)&Cp[(size_t)(m0 + tm + r) * N_ + n0 + tn];
    o[0] = make_float4(acc[r][0], acc[r][1], acc[r][2], acc[r][3]);
    o[1] = make_float4(acc[r][4], acc[r][5], acc[r][6], acc[r][7]);
  }
}

// ---------------------------------------------------------------------------
// K1: pp4[ks][b][n] partial sums of h @ W_h2h^T  (M=256,N=512,K=512, split-K 4)
// tiles 64x64, micro 4x4, BK=32. grid 128 = bt(4) x nt(8) x ks(4)
// h lives at xc[b*1024 + 512 + k]
// ---------------------------------------------------------------------------
__global__ __launch_bounds__(256) void k1_pp(const float* __restrict__ xc, const float* __restrict__ Wh,
                                             float* __restrict__ pp4) {
  int id = blockIdx.x;
  int b0 = (id & 3) * 64;
  int n0 = ((id >> 2) & 7) * 64;
  int ks = id >> 5;
  int kbase = ks * 128;
  __shared__ float As[32][68];
  __shared__ float Bs[32][68];
  int tid = threadIdx.x;
  int tm = (tid >> 4) * 4, tn = (tid & 15) * 4;
  float acc[4][4] = {};
  for (int kk = 0; kk < 128; kk += 32) {
    int k0 = kbase + kk;
#pragma unroll
    for (int i = 0; i < 2; ++i) {
      int f = tid + i * 256;          // 0..511 ; 64 rows x 8 float4
      int row = f >> 3, c4 = (f & 7) * 4;
      float4 va = *(const float4*)&xc[(size_t)(b0 + row) * KX + 512 + k0 + c4];
      As[c4 + 0][row] = va.x; As[c4 + 1][row] = va.y; As[c4 + 2][row] = va.z; As[c4 + 3][row] = va.w;
      float4 vb = *(const float4*)&Wh[(size_t)(n0 + row) * 512 + k0 + c4];
      Bs[c4 + 0][row] = vb.x; Bs[c4 + 1][row] = vb.y; Bs[c4 + 2][row] = vb.z; Bs[c4 + 3][row] = vb.w;
    }
    __syncthreads();
#pragma unroll
    for (int k = 0; k < 32; ++k) {
      float4 a = *(const float4*)&As[k][tm];
      float4 b = *(const float4*)&Bs[k][tn];
      float av[4] = {a.x, a.y, a.z, a.w};
      float bv[4] = {b.x, b.y, b.z, b.w};
#pragma unroll
      for (int r = 0; r < 4; ++r)
#pragma unroll
        for (int c = 0; c < 4; ++c) acc[r][c] += av[r] * bv[c];
    }
    __syncthreads();
  }
  float* o = pp4 + (size_t)ks * (BB * HH);
#pragma unroll
  for (int r = 0; r < 4; ++r)
#pragma unroll
    for (int c = 0; c < 4; ++c) o[(size_t)(b0 + tm + r) * HH + n0 + tn + c] = acc[r][c];
}

// ---------------------------------------------------------------------------
// K2: per-b fused  pp-sum -> score(tanh dot) -> softmax(T=64) -> ctx
// grid 256 (one block per b), 256 threads (4 waves)
// writes ctx into xc[b*1024 + 0..511]
// ---------------------------------------------------------------------------
__global__ __launch_bounds__(256) void k2_attn(const float* __restrict__ proj, const float* __restrict__ pp4,
                                               const float* __restrict__ b_h2h, const float* __restrict__ w_score,
                                               const float* __restrict__ bh, float* __restrict__ xc) {
  int b = blockIdx.x;
  __shared__ float pp_s[512];
  __shared__ float sv_s[512];
  __shared__ float sc_s[64];
  int tid = threadIdx.x;
  for (int k = tid; k < 512; k += 256) {
    pp_s[k] = pp4[(size_t)b * HH + k] + pp4[(size_t)(BB * HH) + b * HH + k] +
              pp4[(size_t)(2 * BB * HH) + b * HH + k] + pp4[(size_t)(3 * BB * HH) + b * HH + k] + b_h2h[k];
    sv_s[k] = w_score[k];
  }
  __syncthreads();
  int wave = tid >> 6, lane = tid & 63;
  for (int t = wave; t < 64; t += 4) {
    const float* pr = &proj[((size_t)b * TT + t) * HH];
    float acc = 0.f;
#pragma unroll
    for (int j = 0; j < 8; ++j) {
      int h = lane + j * 64;
      acc += tanhf(pr[h] + pp_s[h]) * sv_s[h];
    }
#pragma unroll
    for (int off = 32; off > 0; off >>= 1) acc += __shfl_down(acc, off);
    if (lane == 0) sc_s[t] = acc;
  }
  __syncthreads();
  if (wave == 0) {
    float x = sc_s[lane];
    float m = x;
#pragma unroll
    for (int off = 32; off > 0; off >>= 1) m = fmaxf(m, __shfl_xor(m, off));
    float e = __expf(x - m);
    float ssum = e;
#pragma unroll
    for (int off = 32; off > 0; off >>= 1) ssum += __shfl_xor(ssum, off);
    sc_s[lane] = e / ssum;
  }
  __syncthreads();
  float a0 = 0.f, a1 = 0.f;
  for (int t = 0; t < 64; ++t) {
    float w = sc_s[t];
    const float* pb = &bh[((size_t)b * TT + t) * II];
    a0 += w * pb[tid];
    a1 += w * pb[tid + 256];
  }
  xc[(size_t)b * KX + tid] = a0;
  xc[(size_t)b * KX + tid + 256] = a1;
}

// ---------------------------------------------------------------------------
// K3: gates = x @ Wp^T (+bias+onehot col) then fused LSTM pointwise.
// M=256, N=2048 packed(gate-interleaved), K=1024. tiles 64x64, micro 4x4.
// grid 128 = bt(4) x rt(32). Each thread's 4 N-columns = the 4 gates of one j.
// reads xc (ctx|h), writes h into xn[.,512+j] (double buffer) + hs + cbuf.
// ---------------------------------------------------------------------------
__global__ __launch_bounds__(256) void k3_gates(const float* __restrict__ xc, float* __restrict__ xn,
                                                const float* __restrict__ Wp, const float* __restrict__ bp,
                                                const float* __restrict__ Woh, const int* __restrict__ ctxids,
                                                float* __restrict__ cbuf, float* __restrict__ hs, int s) {
  int id = blockIdx.x;
  int b0 = (id & 3) * 64;
  int r0 = (id >> 2) * 64;       // packed-row tile base (64 rows = 16 j x 4 gates)
  __shared__ float As[32][68];
  __shared__ float Bs[32][68];
  __shared__ int cid_s[64];
  int tid = threadIdx.x;
  if (tid < 64) cid_s[tid] = ctxids[(size_t)(b0 + tid) * SS + s];
  int tm = (tid >> 4) * 4, tn = (tid & 15) * 4;
  float acc[4][4] = {};
  for (int k0 = 0; k0 < KX; k0 += 32) {
#pragma unroll
    for (int i = 0; i < 2; ++i) {
      int f = tid + i * 256;
      int row = f >> 3, c4 = (f & 7) * 4;
      float4 va = *(const float4*)&xc[(size_t)(b0 + row) * KX + k0 + c4];
      As[c4 + 0][row] = va.x; As[c4 + 1][row] = va.y; As[c4 + 2][row] = va.z; As[c4 + 3][row] = va.w;
      float4 vb = *(const float4*)&Wp[(size_t)(r0 + row) * KX + k0 + c4];
      Bs[c4 + 0][row] = vb.x; Bs[c4 + 1][row] = vb.y; Bs[c4 + 2][row] = vb.z; Bs[c4 + 3][row] = vb.w;
    }
    __syncthreads();
#pragma unroll
    for (int k = 0; k < 32; ++k) {
      float4 a = *(const float4*)&As[k][tm];
      float4 b = *(const float4*)&Bs[k][tn];
      float av[4] = {a.x, a.y, a.z, a.w};
      float bv[4] = {b.x, b.y, b.z, b.w};
#pragma unroll
      for (int r = 0; r < 4; ++r)
#pragma unroll
        for (int c = 0; c < 4; ++c) acc[r][c] += av[r] * bv[c];
    }
    __syncthreads();
  }
  // epilogue: 4 packed rows (tn..tn+3) are gates i,f,g,o of j = (r0+tn)/4
  int j = (r0 + tn) >> 2;
#pragma unroll
  for (int r = 0; r < 4; ++r) {
    int b = b0 + tm + r;
    int cid = cid_s[tm + r];
    float gi = acc[r][0] + bp[r0 + tn + 0] + Woh[(size_t)(r0 + tn + 0) * CC + cid];
    float gf = acc[r][1] + bp[r0 + tn + 1] + Woh[(size_t)(r0 + tn + 1) * CC + cid];
    float gg = acc[r][2] + bp[r0 + tn + 2] + Woh[(size_t)(r0 + tn + 2) * CC + cid];
    float go = acc[r][3] + bp[r0 + tn + 3] + Woh[(size_t)(r0 + tn + 3) * CC + cid];
    float iv = 1.f / (1.f + __expf(-gi));
    float fv = 1.f / (1.f + __expf(-gf));
    float gv = tanhf(gg);
    float ov = 1.f / (1.f + __expf(-go));
    float cc = fv * cbuf[(size_t)b * HH + j] + iv * gv;
    cbuf[(size_t)b * HH + j] = cc;
    float hv = ov * tanhf(cc);
    xn[(size_t)b * KX + 512 + j] = hv;
    hs[((size_t)b * SS + s) * HH + j] = hv;
  }
}

// ---------------------------------------------------------------------------
// K4: probs = hs @ W_cls^T + b_cls. block per (b,s)=bs, 128 threads (97 active)
// ---------------------------------------------------------------------------
__global__ __launch_bounds__(128) void k4_cls(const float* __restrict__ hsb, const float* __restrict__ Wc,
                                              const float* __restrict__ bc, float* __restrict__ out) {
  int bs = blockIdx.x;
  __shared__ float h_s[512];
  int tid = threadIdx.x;
  for (int k = tid; k < 512; k += 128) h_s[k] = hsb[(size_t)bs * HH + k];
  __syncthreads();
  if (tid < CC) {
    float acc = bc[tid];
    const float* wr = &Wc[(size_t)tid * HH];
    for (int k = 0; k < 512; k += 4) {
      float4 w = *(const float4*)&wr[k];
      acc += w.x * h_s[k] + w.y * h_s[k + 1] + w.z * h_s[k + 2] + w.w * h_s[k + 3];
    }
    out[(size_t)bs * CC + tid] = acc;
  }
}

// ---------------------------------------------------------------------------
extern "C" void kernel_launch(void* const* d_in, const int* in_sizes, int n_in,
                              void* d_out, int out_size, void* d_ws, size_t ws_size,
                              hipStream_t stream) {
  const float* bh      = (const float*)d_in[0];   // [256,64,512]
  const int*   ctxi    = (const int*)d_in[1];     // [256,26]
  // d_in[2]=max_length(25), d_in[3]=train_mode(1): hardcoded (shapes fixed)
  const float* W_i2h   = (const float*)d_in[4];   // [512,512]
  const float* W_h2h   = (const float*)d_in[5];   // [512,512]
  const float* b_h2h   = (const float*)d_in[6];   // [512]
  const float* w_score = (const float*)d_in[7];   // [1,512]
  const float* W_ih    = (const float*)d_in[8];   // [2048,609]
  const float* b_ih    = (const float*)d_in[9];   // [2048]
  const float* W_hh    = (const float*)d_in[10];  // [2048,512]
  const float* b_hh    = (const float*)d_in[11];  // [2048]
  const float* W_cls   = (const float*)d_in[12];  // [97,512]
  const float* b_cls   = (const float*)d_in[13];  // [97]
  float* out = (float*)d_out;

  // workspace layout (f32), ~58.3 MB total
  float* xA   = (float*)d_ws;            // [256][1024]  (ctx | h) step parity 0
  float* xB   = xA + BB * KX;            // [256][1024]  parity 1
  float* cbuf = xB + BB * KX;            // [256][512]
  float* pp4  = cbuf + BB * HH;          // [4][256][512]
  float* hsb  = pp4 + 4 * BB * HH;       // [256][26][512]
  float* proj = hsb + BB * SS * HH;      // [16384][512]
  float* Wp   = proj + (size_t)BB * TT * HH;  // [2048][1024]
  float* bp   = Wp + (size_t)GG * KX;    // [2048]
  float* Woh  = bp + GG;                 // [2048][97]

  // zero xA,xB,cbuf (contiguous 655360 floats = 163840 float4)
  k_init<<<dim3(640), dim3(256), 0, stream>>>((float4*)d_ws, 163840);
  k_prep<<<dim3(GG), dim3(256), 0, stream>>>(W_ih, b_ih, W_hh, b_hh, Wp, bp, Woh);
  k0_proj<<<dim3(512), dim3(256), 0, stream>>>(bh, W_i2h, proj);

  for (int s = 0; s < SS; ++s) {
    float* xc = (s & 1) ? xB : xA;
    float* xn = (s & 1) ? xA : xB;
    k1_pp<<<dim3(128), dim3(256), 0, stream>>>(xc, W_h2h, pp4);
    k2_attn<<<dim3(256), dim3(256), 0, stream>>>(proj, pp4, b_h2h, w_score, bh, xc);
    k3_gates<<<dim3(128), dim3(256), 0, stream>>>(xc, xn, Wp, bp, Woh, ctxi, cbuf, hsb, s);
  }
  k4_cls<<<dim3(BB * SS), dim3(128), 0, stream>>>(hsb, W_cls, b_cls, out);
}

// Round 4
// 2270.798 us; speedup vs baseline: 1.4602x; 1.4602x over previous
//
#include <hip/hip_runtime.h>

#define BB 256
#define TT 64
#define HH 512
#define CC 97
#define SS 26
#define KX 1024

typedef __attribute__((ext_vector_type(8))) short short8;
typedef __attribute__((ext_vector_type(4))) float f32x4;

#define MFMA16(a, b, c) __builtin_amdgcn_mfma_f32_16x16x32_bf16((a), (b), (c), 0, 0, 0)

__device__ __forceinline__ unsigned short f2bf(float x) {
  unsigned int u = __float_as_uint(x);
  u += 0x7FFFu + ((u >> 16) & 1u);
  return (unsigned short)(u >> 16);
}
__device__ __forceinline__ float bf2f(unsigned short b) {
  return __uint_as_float(((unsigned int)b) << 16);
}
// split 8 f32 (two float4) into bf16 hi + lo parts
__device__ __forceinline__ void split8(float4 a, float4 b, short8& vh, short8& vl) {
  float x[8] = {a.x, a.y, a.z, a.w, b.x, b.y, b.z, b.w};
#pragma unroll
  for (int i = 0; i < 8; ++i) {
    unsigned short h = f2bf(x[i]);
    vh[i] = (short)h;
    vl[i] = (short)f2bf(x[i] - bf2f(h));
  }
}

// ---------------------------------------------------------------------------
__global__ __launch_bounds__(256) void k_init(float4* __restrict__ p, int n4) {
  int i = blockIdx.x * 256 + threadIdx.x;
  if (i < n4) p[i] = make_float4(0.f, 0.f, 0.f, 0.f);
}

// ---------------------------------------------------------------------------
// prep: pack W_ih[:, :512] | W_hh into Wp_hi/lo [2048][1024] bf16, packed row
// p = ntile*64 + q*16 + jlow  (j = ntile*16+jlow, gate row g = q*512 + j)
// ---------------------------------------------------------------------------
__global__ __launch_bounds__(256) void k_prep_wp(const float* __restrict__ W_ih, const float* __restrict__ b_ih,
                                                 const float* __restrict__ W_hh, const float* __restrict__ b_hh,
                                                 unsigned short* __restrict__ Wp_hi, unsigned short* __restrict__ Wp_lo,
                                                 float* __restrict__ bp2, float* __restrict__ Woh2) {
  int p = blockIdx.x;
  int ntile = p >> 6, q = (p >> 4) & 3, jl = p & 15;
  int g = q * 512 + ntile * 16 + jl;
  int tid = threadIdx.x;
  for (int k = tid; k < 1024; k += 256) {
    float v = (k < 512) ? W_ih[(size_t)g * 609 + k] : W_hh[(size_t)g * 512 + (k - 512)];
    unsigned short h = f2bf(v);
    Wp_hi[(size_t)p * 1024 + k] = h;
    Wp_lo[(size_t)p * 1024 + k] = f2bf(v - bf2f(h));
  }
  if (tid < CC) Woh2[(size_t)p * CC + tid] = W_ih[(size_t)g * 609 + 512 + tid];
  if (tid == 0) bp2[p] = b_ih[g] + b_hh[g];
}

__global__ __launch_bounds__(256) void k_prep_w2h(const float* __restrict__ W_h2h,
                                                  unsigned short* __restrict__ Whi, unsigned short* __restrict__ Wlo) {
  int n = blockIdx.x;
  int tid = threadIdx.x;
  for (int k = tid; k < 512; k += 256) {
    float v = W_h2h[(size_t)n * 512 + k];
    unsigned short h = f2bf(v);
    Whi[(size_t)n * 512 + k] = h;
    Wlo[(size_t)n * 512 + k] = f2bf(v - bf2f(h));
  }
}

// ---------------------------------------------------------------------------
// K0: proj = bh @ W_i2h^T  (M=16384,N=512,K=512) hi/lo bf16 MFMA, out bf16.
// grid 1024 = 128 m-tiles x 8 n-tiles; tile 128x64; 4 waves (2M x 2N).
// ---------------------------------------------------------------------------
__global__ __launch_bounds__(256) void k0_proj(const float* __restrict__ A, const float* __restrict__ Bw,
                                               unsigned short* __restrict__ projb) {
  __shared__ short Ah[128][40], Al[128][40], Bh[64][40], Bl[64][40];
  int mt = blockIdx.x >> 3, nt = blockIdx.x & 7;
  int m0 = mt * 128, n0 = nt * 64;
  int tid = threadIdx.x;
  int w = tid >> 6, l = tid & 63;
  int wm = w >> 1, wn = w & 1;
  f32x4 acc[4][2];
#pragma unroll
  for (int i = 0; i < 4; ++i)
#pragma unroll
    for (int j = 0; j < 2; ++j) acc[i][j] = (f32x4){0.f, 0.f, 0.f, 0.f};
  int ar_s = tid >> 1, akc = (tid & 1) * 16;
  int br_s = tid >> 2, bkc = (tid & 3) * 8;
  for (int k0 = 0; k0 < 512; k0 += 32) {
    {
      const float* s = &A[(size_t)(m0 + ar_s) * 512 + k0 + akc];
      short8 vh, vl;
      split8(*(const float4*)s, *(const float4*)(s + 4), vh, vl);
      *(short8*)&Ah[ar_s][akc] = vh; *(short8*)&Al[ar_s][akc] = vl;
      split8(*(const float4*)(s + 8), *(const float4*)(s + 12), vh, vl);
      *(short8*)&Ah[ar_s][akc + 8] = vh; *(short8*)&Al[ar_s][akc + 8] = vl;
      const float* sb = &Bw[(size_t)(n0 + br_s) * 512 + k0 + bkc];
      split8(*(const float4*)sb, *(const float4*)(sb + 4), vh, vl);
      *(short8*)&Bh[br_s][bkc] = vh; *(short8*)&Bl[br_s][bkc] = vl;
    }
    __syncthreads();
    int ko = (l >> 4) * 8;
    short8 ah[4], al8[4];
#pragma unroll
    for (int mf = 0; mf < 4; ++mf) {
      int ar = wm * 64 + mf * 16 + (l & 15);
      ah[mf] = *(short8*)&Ah[ar][ko];
      al8[mf] = *(short8*)&Al[ar][ko];
    }
#pragma unroll
    for (int nf = 0; nf < 2; ++nf) {
      int br = wn * 32 + nf * 16 + (l & 15);
      short8 bh8 = *(short8*)&Bh[br][ko];
      short8 bl8 = *(short8*)&Bl[br][ko];
#pragma unroll
      for (int mf = 0; mf < 4; ++mf) {
        acc[mf][nf] = MFMA16(ah[mf], bh8, acc[mf][nf]);
        acc[mf][nf] = MFMA16(ah[mf], bl8, acc[mf][nf]);
        acc[mf][nf] = MFMA16(al8[mf], bh8, acc[mf][nf]);
      }
    }
    __syncthreads();
  }
#pragma unroll
  for (int mf = 0; mf < 4; ++mf)
#pragma unroll
    for (int nf = 0; nf < 2; ++nf)
#pragma unroll
      for (int r = 0; r < 4; ++r) {
        int m = m0 + wm * 64 + mf * 16 + (l >> 4) * 4 + r;
        int n = n0 + wn * 32 + nf * 16 + (l & 15);
        projb[(size_t)m * 512 + n] = f2bf(acc[mf][nf][r]);
      }
}

// ---------------------------------------------------------------------------
// K1: pp = h @ W_h2h^T  (M=256,N=512,K=512) hi/lo MFMA. grid 32 (4 bt x 8 nt),
// tile 64x64, 4 waves (2x2), wave 32x32 (2x2 frags).
// ---------------------------------------------------------------------------
__global__ __launch_bounds__(256) void k1_pp(const float* __restrict__ xc, const unsigned short* __restrict__ Whi,
                                             const unsigned short* __restrict__ Wlo, float* __restrict__ pp) {
  __shared__ short Ah[64][40], Al[64][40], Bh[64][40], Bl[64][40];
  int bt = blockIdx.x & 3, nt = blockIdx.x >> 2;
  int b0 = bt * 64, n0 = nt * 64;
  int tid = threadIdx.x, w = tid >> 6, l = tid & 63;
  int wm = w >> 1, wn = w & 1;
  f32x4 acc[2][2];
#pragma unroll
  for (int i = 0; i < 2; ++i)
#pragma unroll
    for (int j = 0; j < 2; ++j) acc[i][j] = (f32x4){0.f, 0.f, 0.f, 0.f};
  int row = tid >> 2, kc = (tid & 3) * 8;
  for (int k0 = 0; k0 < 512; k0 += 32) {
    {
      const float* s = &xc[(size_t)(b0 + row) * KX + 512 + k0 + kc];
      short8 vh, vl;
      split8(*(const float4*)s, *(const float4*)(s + 4), vh, vl);
      *(short8*)&Ah[row][kc] = vh; *(short8*)&Al[row][kc] = vl;
      *(short8*)&Bh[row][kc] = *(const short8*)&Whi[(size_t)(n0 + row) * 512 + k0 + kc];
      *(short8*)&Bl[row][kc] = *(const short8*)&Wlo[(size_t)(n0 + row) * 512 + k0 + kc];
    }
    __syncthreads();
    int ko = (l >> 4) * 8;
    short8 ah[2], al8[2];
#pragma unroll
    for (int mf = 0; mf < 2; ++mf) {
      int ar = wm * 32 + mf * 16 + (l & 15);
      ah[mf] = *(short8*)&Ah[ar][ko];
      al8[mf] = *(short8*)&Al[ar][ko];
    }
#pragma unroll
    for (int nf = 0; nf < 2; ++nf) {
      int br = wn * 32 + nf * 16 + (l & 15);
      short8 bh8 = *(short8*)&Bh[br][ko];
      short8 bl8 = *(short8*)&Bl[br][ko];
#pragma unroll
      for (int mf = 0; mf < 2; ++mf) {
        acc[mf][nf] = MFMA16(ah[mf], bh8, acc[mf][nf]);
        acc[mf][nf] = MFMA16(ah[mf], bl8, acc[mf][nf]);
        acc[mf][nf] = MFMA16(al8[mf], bh8, acc[mf][nf]);
      }
    }
    __syncthreads();
  }
#pragma unroll
  for (int mf = 0; mf < 2; ++mf)
#pragma unroll
    for (int nf = 0; nf < 2; ++nf)
#pragma unroll
      for (int r = 0; r < 4; ++r) {
        int m = b0 + wm * 32 + mf * 16 + (l >> 4) * 4 + r;
        int n = n0 + wn * 32 + nf * 16 + (l & 15);
        pp[(size_t)m * 512 + n] = acc[mf][nf][r];
      }
}

// ---------------------------------------------------------------------------
// K2: per-b fused score(tanh dot, bf16 proj) -> softmax -> ctx. grid 256.
// pp+b_h2h and w_score live in registers (8 h-values per lane).
// ---------------------------------------------------------------------------
__global__ __launch_bounds__(256) void k2_attn(const unsigned short* __restrict__ projb, const float* __restrict__ pp,
                                               const float* __restrict__ b_h2h, const float* __restrict__ w_score,
                                               const float* __restrict__ bh, float* __restrict__ xc) {
  int b = blockIdx.x;
  __shared__ float sc_s[64];
  int tid = threadIdx.x;
  int wave = tid >> 6, lane = tid & 63;
  float ppv[8], svv[8];
  {
    const float* p0 = &pp[(size_t)b * 512 + lane * 8];
    float4 a0 = *(const float4*)p0, a1 = *(const float4*)(p0 + 4);
    float4 c0 = *(const float4*)&b_h2h[lane * 8], c1 = *(const float4*)&b_h2h[lane * 8 + 4];
    float4 d0 = *(const float4*)&w_score[lane * 8], d1 = *(const float4*)&w_score[lane * 8 + 4];
    ppv[0] = a0.x + c0.x; ppv[1] = a0.y + c0.y; ppv[2] = a0.z + c0.z; ppv[3] = a0.w + c0.w;
    ppv[4] = a1.x + c1.x; ppv[5] = a1.y + c1.y; ppv[6] = a1.z + c1.z; ppv[7] = a1.w + c1.w;
    svv[0] = d0.x; svv[1] = d0.y; svv[2] = d0.z; svv[3] = d0.w;
    svv[4] = d1.x; svv[5] = d1.y; svv[6] = d1.z; svv[7] = d1.w;
  }
  for (int t = wave; t < 64; t += 4) {
    const unsigned short* pr = &projb[((size_t)b * 64 + t) * 512 + lane * 8];
    uint4 raw = *(const uint4*)pr;
    unsigned int uu[4] = {raw.x, raw.y, raw.z, raw.w};
    float acc = 0.f;
#pragma unroll
    for (int i = 0; i < 4; ++i) {
      float f0 = bf2f((unsigned short)(uu[i] & 0xFFFFu));
      float f1 = bf2f((unsigned short)(uu[i] >> 16));
      acc += tanhf(f0 + ppv[2 * i]) * svv[2 * i];
      acc += tanhf(f1 + ppv[2 * i + 1]) * svv[2 * i + 1];
    }
#pragma unroll
    for (int off = 32; off > 0; off >>= 1) acc += __shfl_down(acc, off);
    if (lane == 0) sc_s[t] = acc;
  }
  __syncthreads();
  if (wave == 0) {
    float x = sc_s[lane];
    float m = x;
#pragma unroll
    for (int off = 32; off > 0; off >>= 1) m = fmaxf(m, __shfl_xor(m, off));
    float e = __expf(x - m);
    float ssum = e;
#pragma unroll
    for (int off = 32; off > 0; off >>= 1) ssum += __shfl_xor(ssum, off);
    sc_s[lane] = e / ssum;
  }
  __syncthreads();
  float a0 = 0.f, a1 = 0.f;
  for (int t = 0; t < 64; ++t) {
    float wgt = sc_s[t];
    const float* pb = &bh[((size_t)b * 64 + t) * 512];
    a0 += wgt * pb[tid];
    a1 += wgt * pb[tid + 256];
  }
  xc[(size_t)b * KX + tid] = a0;
  xc[(size_t)b * KX + tid + 256] = a1;
}

// ---------------------------------------------------------------------------
// K3: gates = [ctx|h] @ Wp^T (packed), hi/lo MFMA, fused LSTM pointwise.
// grid 128 (4 bt x 32 ntile), tile 64x64, 4 waves stacked in M,
// wave = 1 m-frag x 4 n-frags; frag nf = gate nf of j = jb + (l&15).
// ---------------------------------------------------------------------------
__global__ __launch_bounds__(256) void k3_gates(const float* __restrict__ xc, float* __restrict__ xn,
                                                const unsigned short* __restrict__ Wp_hi, const unsigned short* __restrict__ Wp_lo,
                                                const float* __restrict__ bp2, const float* __restrict__ Woh2,
                                                const int* __restrict__ ctxids, float* __restrict__ cbuf,
                                                float* __restrict__ hs, int s) {
  __shared__ short Ah[64][40], Al[64][40], Bh[64][40], Bl[64][40];
  __shared__ int cid_s[64];
  int bt = blockIdx.x & 3, ntile = blockIdx.x >> 2;
  int b0 = bt * 64, n0 = ntile * 64, jb = ntile * 16;
  int tid = threadIdx.x, w = tid >> 6, l = tid & 63;
  if (tid < 64) cid_s[tid] = ctxids[(size_t)(b0 + tid) * SS + s];
  f32x4 acc[4];
#pragma unroll
  for (int i = 0; i < 4; ++i) acc[i] = (f32x4){0.f, 0.f, 0.f, 0.f};
  int row = tid >> 2, kc = (tid & 3) * 8;
  for (int k0 = 0; k0 < 1024; k0 += 32) {
    {
      const float* sp = &xc[(size_t)(b0 + row) * KX + k0 + kc];
      short8 vh, vl;
      split8(*(const float4*)sp, *(const float4*)(sp + 4), vh, vl);
      *(short8*)&Ah[row][kc] = vh; *(short8*)&Al[row][kc] = vl;
      *(short8*)&Bh[row][kc] = *(const short8*)&Wp_hi[(size_t)(n0 + row) * 1024 + k0 + kc];
      *(short8*)&Bl[row][kc] = *(const short8*)&Wp_lo[(size_t)(n0 + row) * 1024 + k0 + kc];
    }
    __syncthreads();
    int ko = (l >> 4) * 8;
    int ar = w * 16 + (l & 15);
    short8 ah = *(short8*)&Ah[ar][ko];
    short8 al8 = *(short8*)&Al[ar][ko];
#pragma unroll
    for (int nf = 0; nf < 4; ++nf) {
      int br = nf * 16 + (l & 15);
      short8 bh8 = *(short8*)&Bh[br][ko];
      short8 bl8 = *(short8*)&Bl[br][ko];
      acc[nf] = MFMA16(ah, bh8, acc[nf]);
      acc[nf] = MFMA16(ah, bl8, acc[nf]);
      acc[nf] = MFMA16(al8, bh8, acc[nf]);
    }
    __syncthreads();
  }
  int jl = l & 15, j = jb + jl;
  float bia[4];
#pragma unroll
  for (int q = 0; q < 4; ++q) bia[q] = bp2[n0 + q * 16 + jl];
#pragma unroll
  for (int r = 0; r < 4; ++r) {
    int br_ = b0 + w * 16 + (l >> 4) * 4 + r;
    int cid = cid_s[w * 16 + (l >> 4) * 4 + r];
    float gi = acc[0][r] + bia[0] + Woh2[(size_t)(n0 + 0 + jl) * CC + cid];
    float gf = acc[1][r] + bia[1] + Woh2[(size_t)(n0 + 16 + jl) * CC + cid];
    float gg = acc[2][r] + bia[2] + Woh2[(size_t)(n0 + 32 + jl) * CC + cid];
    float go = acc[3][r] + bia[3] + Woh2[(size_t)(n0 + 48 + jl) * CC + cid];
    float iv = 1.f / (1.f + __expf(-gi));
    float fv = 1.f / (1.f + __expf(-gf));
    float gv = tanhf(gg);
    float ov = 1.f / (1.f + __expf(-go));
    float cNew = fv * cbuf[(size_t)br_ * HH + j] + iv * gv;
    cbuf[(size_t)br_ * HH + j] = cNew;
    float hv = ov * tanhf(cNew);
    xn[(size_t)br_ * KX + 512 + j] = hv;
    hs[((size_t)br_ * SS + s) * HH + j] = hv;
  }
}

// ---------------------------------------------------------------------------
// K4: probs = hs @ W_cls^T + b_cls. grid 208 (32 bs-rows each), tile 32x112(97),
// micro 2x7, K-chunk 32.
// ---------------------------------------------------------------------------
__global__ __launch_bounds__(256) void k4_cls(const float* __restrict__ hsb, const float* __restrict__ Wc,
                                              const float* __restrict__ bc, float* __restrict__ out) {
  __shared__ float Hs[32][36];
  __shared__ float Wcs[112][36];
  int bs0 = blockIdx.x * 32;
  int tid = threadIdx.x;
  int rt = tid >> 4, ct = tid & 15;
  float acc[2][7] = {};
  for (int k0 = 0; k0 < 512; k0 += 32) {
    {
      int row = tid >> 3, kc = (tid & 7) * 4;
      float4 v = *(const float4*)&hsb[(size_t)(bs0 + row) * 512 + k0 + kc];
      Hs[row][kc] = v.x; Hs[row][kc + 1] = v.y; Hs[row][kc + 2] = v.z; Hs[row][kc + 3] = v.w;
    }
    for (int i = tid; i < 776; i += 256) {
      int n = i >> 3, kc = (i & 7) * 4;
      float4 v = *(const float4*)&Wc[(size_t)n * 512 + k0 + kc];
      Wcs[n][kc] = v.x; Wcs[n][kc + 1] = v.y; Wcs[n][kc + 2] = v.z; Wcs[n][kc + 3] = v.w;
    }
    __syncthreads();
#pragma unroll 4
    for (int kk = 0; kk < 32; ++kk) {
      float a0 = Hs[2 * rt][kk], a1 = Hs[2 * rt + 1][kk];
#pragma unroll
      for (int cc = 0; cc < 7; ++cc) {
        float wv = Wcs[ct * 7 + cc][kk];
        acc[0][cc] += a0 * wv;
        acc[1][cc] += a1 * wv;
      }
    }
    __syncthreads();
  }
#pragma unroll
  for (int rr = 0; rr < 2; ++rr)
#pragma unroll
    for (int cc = 0; cc < 7; ++cc) {
      int c = ct * 7 + cc;
      if (c < CC) out[(size_t)(bs0 + 2 * rt + rr) * CC + c] = acc[rr][cc] + bc[c];
    }
}

// ---------------------------------------------------------------------------
extern "C" void kernel_launch(void* const* d_in, const int* in_sizes, int n_in,
                              void* d_out, int out_size, void* d_ws, size_t ws_size,
                              hipStream_t stream) {
  const float* bh      = (const float*)d_in[0];   // [256,64,512]
  const int*   ctxi    = (const int*)d_in[1];     // [256,26]
  const float* W_i2h   = (const float*)d_in[4];   // [512,512]
  const float* W_h2h   = (const float*)d_in[5];   // [512,512]
  const float* b_h2h   = (const float*)d_in[6];   // [512]
  const float* w_score = (const float*)d_in[7];   // [1,512]
  const float* W_ih    = (const float*)d_in[8];   // [2048,609]
  const float* b_ih    = (const float*)d_in[9];   // [2048]
  const float* W_hh    = (const float*)d_in[10];  // [2048,512]
  const float* b_hh    = (const float*)d_in[11];  // [2048]
  const float* W_cls   = (const float*)d_in[12];  // [97,512]
  const float* b_cls   = (const float*)d_in[13];  // [97]
  float* out = (float*)d_out;

  // workspace layout
  float* xA   = (float*)d_ws;                       // [256][1024]
  float* xB   = xA + (size_t)BB * KX;               // [256][1024]
  float* cbuf = xB + (size_t)BB * KX;               // [256][512]
  float* pp   = cbuf + (size_t)BB * HH;             // [256][512]
  float* hsb  = pp + (size_t)BB * HH;               // [256][26][512]
  unsigned short* projb  = (unsigned short*)(hsb + (size_t)BB * SS * HH);  // [16384][512] bf16
  unsigned short* Wp_hi  = projb + (size_t)16384 * 512;                    // [2048][1024] bf16
  unsigned short* Wp_lo  = Wp_hi + (size_t)2048 * 1024;
  unsigned short* W2h_hi = Wp_lo + (size_t)2048 * 1024;                    // [512][512] bf16
  unsigned short* W2h_lo = W2h_hi + (size_t)512 * 512;
  float* bp2  = (float*)(W2h_lo + (size_t)512 * 512);                      // [2048]
  float* Woh2 = bp2 + 2048;                                                // [2048][97]

  // zero xA, xB, cbuf (contiguous 655360 floats = 163840 float4)
  k_init<<<dim3(640), dim3(256), 0, stream>>>((float4*)d_ws, 163840);
  k_prep_wp<<<dim3(2048), dim3(256), 0, stream>>>(W_ih, b_ih, W_hh, b_hh, Wp_hi, Wp_lo, bp2, Woh2);
  k_prep_w2h<<<dim3(512), dim3(256), 0, stream>>>(W_h2h, W2h_hi, W2h_lo);
  k0_proj<<<dim3(1024), dim3(256), 0, stream>>>(bh, W_i2h, projb);

  for (int s = 0; s < SS; ++s) {
    float* xc = (s & 1) ? xB : xA;
    float* xn = (s & 1) ? xA : xB;
    k1_pp<<<dim3(32), dim3(256), 0, stream>>>(xc, W2h_hi, W2h_lo, pp);
    k2_attn<<<dim3(256), dim3(256), 0, stream>>>(projb, pp, b_h2h, w_score, bh, xc);
    k3_gates<<<dim3(128), dim3(256), 0, stream>>>(xc, xn, Wp_hi, Wp_lo, bp2, Woh2, ctxi, cbuf, hsb, s);
  }
  k4_cls<<<dim3(208), dim3(256), 0, stream>>>(hsb, W_cls, b_cls, out);
}